// Round 10
// baseline (2737.834 us; speedup 1.0000x reference)
//
#include <hip/hip_runtime.h>
#include <cmath>
#include <cstdint>

#define N_F    2000
#define N_I    500
#define N_O    500
#define N_ALL  3000
#define C      8
#define H      16000
#define B      256
#define E_FF   40000
#define E_IF   5000
#define E_FO   2000
#define E_ALL  47000
#define LAYERS 10
#define EPSF   1e-5f
#define RED    32     // reduction slices (done by last 32 arriving blocks)

// ---- bf16 helpers (RNE) ----
static __device__ __forceinline__ unsigned short f2bf(float f) {
    unsigned int u = __float_as_uint(f);
    unsigned int r = (u + 0x7FFFu + ((u >> 16) & 1u)) >> 16;
    return (unsigned short)r;
}
static __device__ __forceinline__ float bf2f(unsigned short h) {
    return __uint_as_float(((unsigned int)h) << 16);
}

// ---------------- CSR build (deterministic after k_wsort) ----------------

__global__ void k_zero_cnt(int* cntA, int* cntB, int* cntC, int* cntD, int* cnt_red) {
    int tid = threadIdx.x;
    for (int i = tid; i < N_F; i += 1024) { cntA[i] = 0; cntB[i] = 0; cntC[i] = 0; }
    for (int i = tid; i < N_O; i += 1024) cntD[i] = 0;
    if (tid < LAYERS) cnt_red[tid] = 0;
}

__global__ void k_count(const int* __restrict__ src, const int* __restrict__ dst,
                        int* cntA, int* cntB, int* cntC, int* cntD) {
    int e = blockIdx.x * 256 + threadIdx.x;
    if (e >= E_ALL) return;
    int s = src[e], d = dst[e];
    if (e < E_FF)             { atomicAdd(&cntA[d], 1); atomicAdd(&cntB[d], 1); atomicAdd(&cntC[s], 1); }
    else if (e < E_FF + E_IF) { atomicAdd(&cntA[d], 1); }
    else                      { atomicAdd(&cntD[d - (N_F + N_I)], 1); }
}

// 4 single-block scans: A(dst,FF+IF), B(dst,FF only), C(src,FF), D(dst,FO)
__global__ void k_scan(const int* cntA, const int* cntB, const int* cntC, const int* cntD,
                       int* rsA, int* rsB2, int* rsC, int* rsD,
                       int* curA, int* curB, int* curC, int* curD) {
    const int* cnt; int* rs; int* cur; int len;
    if      (blockIdx.x == 0) { cnt = cntA; rs = rsA;  cur = curA; len = N_F; }
    else if (blockIdx.x == 1) { cnt = cntB; rs = rsB2; cur = curB; len = N_F; }
    else if (blockIdx.x == 2) { cnt = cntC; rs = rsC;  cur = curC; len = N_F; }
    else                      { cnt = cntD; rs = rsD;  cur = curD; len = N_O; }
    __shared__ int buf[1024];
    __shared__ int carry;
    int tid = threadIdx.x;
    if (tid == 0) carry = 0;
    __syncthreads();
    for (int base0 = 0; base0 < len; base0 += 1024) {
        int i = base0 + tid;
        int v = (i < len) ? cnt[i] : 0;
        buf[tid] = v;
        __syncthreads();
        for (int off = 1; off < 1024; off <<= 1) {
            int t = (tid >= off) ? buf[tid - off] : 0;
            __syncthreads();
            buf[tid] += t;
            __syncthreads();
        }
        int excl = carry + buf[tid] - v;
        if (i < len) { rs[i] = excl; cur[i] = excl; }
        int tot = buf[1023];
        __syncthreads();
        if (tid == 0) carry += tot;
        __syncthreads();
    }
    if (tid == 0) rs[len] = carry;
}

__global__ void k_fill(const int* __restrict__ src, const int* __restrict__ dst,
                       int* curA, int* curC, int* curD,
                       int* eidA, int* eidC, int* eidD) {
    int e = blockIdx.x * 256 + threadIdx.x;
    if (e >= E_ALL) return;
    int s = src[e], d = dst[e];
    if (e < E_FF) {
        int a = atomicAdd(&curA[d], 1); eidA[a] = e;
        int p = atomicAdd(&curC[s], 1); eidC[p] = e;
    } else if (e < E_FF + E_IF) {
        int a = atomicAdd(&curA[d], 1); eidA[a] = e;
    } else {
        int k = atomicAdd(&curD[d - (N_F + N_I)], 1); eidD[k] = e;
    }
}

// canonicalize: wave rank-sort each list ascending by edge id. A(2000), C(2000), D(500).
__global__ void k_wsort(const int* __restrict__ rsA, int* eidA,
                        const int* __restrict__ rsC, int* eidC,
                        const int* __restrict__ rsD, int* eidD) {
    int w = blockIdx.x * 4 + (threadIdx.x >> 6);
    int lane = threadIdx.x & 63;
    const int* rs; int* eid; int n;
    if      (w < 2000) { rs = rsA; eid = eidA; n = w; }
    else if (w < 4000) { rs = rsC; eid = eidC; n = w - 2000; }
    else if (w < 4500) { rs = rsD; eid = eidD; n = w - 4000; }
    else return;
    int beg = rs[n], end = rs[n + 1], len = end - beg;
    if (len <= 1) return;
    if (len <= 64) {
        int v = (lane < len) ? eid[beg + lane] : 0x7fffffff;
        int rank = 0;
        for (int j = 0; j < 64; ++j) {
            int o = __shfl(v, j, 64);
            rank += (o < v) ? 1 : 0;
        }
        if (lane < len) eid[beg + rank] = v;
    } else if (lane == 0) {
        for (int i = beg + 1; i < end; ++i) {
            int key = eid[i];
            int j = i - 1;
            while (j >= beg && eid[j] > key) { eid[j + 1] = eid[j]; --j; }
            eid[j + 1] = key;
        }
    }
}

// posB[e] = dst-CSR position j for FF edge e; jw1[j] = w1[e]  (FF edges are the
// first cntB[n] entries of node n's sorted A-list, since FF ids < IF ids)
__global__ void k_posB(const int* __restrict__ rsA, const int* __restrict__ eidA,
                       const int* __restrict__ cntB, const int* __restrict__ rsB2,
                       const float* __restrict__ w1, int* posB, float* jw1) {
    int n = blockIdx.x * 256 + threadIdx.x;
    if (n >= N_F) return;
    int a0 = rsA[n], j0 = rsB2[n], m = cntB[n];
    for (int k = 0; k < m; ++k) {
        int e = eidA[a0 + k];
        int j = j0 + k;
        posB[e] = j;
        #pragma unroll
        for (int c = 0; c < C; ++c) jw1[j * C + c] = w1[e * C + c];
    }
}

// jposC[p] = posB[eidC[p]]; w2C[p] = w2[eidC[p]]
__global__ void k_posC(const int* __restrict__ eidC, const int* __restrict__ posB,
                       const float* __restrict__ w2, int* jposC, float* w2C) {
    int p = blockIdx.x * 256 + threadIdx.x;
    if (p >= E_FF) return;
    int e = eidC[p];
    jposC[p] = posB[e];
    #pragma unroll
    for (int c = 0; c < C; ++c) w2C[p * C + c] = w2[e * C + c];
}

// ---------------- init ----------------

// x (B, N_ALL) -> xT (N_ALL, B)
__global__ void k_xT(const float* __restrict__ x, float* __restrict__ xT) {
    __shared__ float t[32][33];
    int tx = threadIdx.x, ty = threadIdx.y;
    int n = blockIdx.x * 32 + tx, b = blockIdx.y * 32 + ty;
    if (n < N_ALL) t[ty][tx] = x[b * N_ALL + n];
    __syncthreads();
    int n2 = blockIdx.x * 32 + ty, b2 = blockIdx.y * 32 + tx;
    if (n2 < N_ALL) xT[n2 * B + b2] = t[tx][ty];
}

// base[n][c][b] = sum_{FF+IF e->n} w1[e][c]*x[src_e][b] + b1[n*C+c]; bb[n][c] = sum w1[e][c]*b2[e]
__global__ void k_base(const float* __restrict__ xT, const float* __restrict__ w1,
                       const float* __restrict__ b1, const float* __restrict__ b2,
                       const int* __restrict__ rsA, const int* __restrict__ eidA,
                       const int* __restrict__ srcv,
                       float* __restrict__ baseG, float* __restrict__ bbG) {
    int n = blockIdx.x, tid = threadIdx.x;
    int beg = rsA[n], end = rsA[n + 1];
    float acc[C] = {0.f,0.f,0.f,0.f,0.f,0.f,0.f,0.f};
    float bba[C] = {0.f,0.f,0.f,0.f,0.f,0.f,0.f,0.f};
    const float4* w14 = (const float4*)w1;
    for (int a = beg; a < end; ++a) {
        int e = eidA[a];
        float xv = xT[srcv[e] * B + tid];
        float bv = b2[e];
        float4 u0 = w14[e * 2], u1 = w14[e * 2 + 1];
        acc[0] += u0.x * xv; acc[1] += u0.y * xv; acc[2] += u0.z * xv; acc[3] += u0.w * xv;
        acc[4] += u1.x * xv; acc[5] += u1.y * xv; acc[6] += u1.z * xv; acc[7] += u1.w * xv;
        bba[0] += u0.x * bv; bba[1] += u0.y * bv; bba[2] += u0.z * bv; bba[3] += u0.w * bv;
        bba[4] += u1.x * bv; bba[5] += u1.y * bv; bba[6] += u1.z * bv; bba[7] += u1.w * bv;
    }
    #pragma unroll
    for (int c = 0; c < C; ++c) baseG[(n * C + c) * B + tid] = acc[c] + b1[n * C + c];
    if (tid == 0) {
        #pragma unroll
        for (int c = 0; c < C; ++c) bbG[n * C + c] = bba[c];
    }
}

// ---------------- per-layer pipeline (2 kernels/layer) ----------------
// q stored in dst-CSR order j: f_hidstat reads CONTIGUOUS [rsB2[n], rsB2[n+1]) rows;
// f_upd scatters to qbf[jposC[p]]. Stat reduction fused into f_hidstat.
// Spin discipline (round-8 lesson): only tid 0 polls, RELAXED load (no cache
// invalidation), s_sleep between polls; one __threadfence() after exit = acquire.

__global__ __launch_bounds__(256) void f_hidstat(
    const float* __restrict__ baseG, const float* __restrict__ bbG,
    const float* __restrict__ jw1, const unsigned short* __restrict__ qbf,
    const int* __restrict__ rsB2,
    unsigned short* __restrict__ hidbf, float* __restrict__ bp,
    float* __restrict__ p2, int* __restrict__ cnt_red, int t) {
    int n = blockIdx.x, tid = threadIdx.x;
    const float4* jw14 = (const float4*)jw1;
    float tf = (float)t;
    float hid[C];
    #pragma unroll
    for (int c = 0; c < C; ++c) hid[c] = baseG[(n * C + c) * B + tid] + tf * bbG[n * C + c];
    if (t > 0) {
        int beg = rsB2[n], end = rsB2[n + 1];
        for (int j = beg; j < end; ++j) {
            float qv = bf2f(qbf[j * B + tid]);
            float4 u0 = jw14[j * 2], u1 = jw14[j * 2 + 1];
            hid[0] += u0.x * qv; hid[1] += u0.y * qv; hid[2] += u0.z * qv; hid[3] += u0.w * qv;
            hid[4] += u1.x * qv; hid[5] += u1.y * qv; hid[6] += u1.z * qv; hid[7] += u1.w * qv;
        }
    }
    float s1 = 0.f, s2 = 0.f;
    #pragma unroll
    for (int c = 0; c < C; ++c) {
        hidbf[(n * C + c) * B + tid] = f2bf(hid[c]);
        s1 += hid[c]; s2 += hid[c] * hid[c];
    }
    bp[(n * 2 + 0) * B + tid] = s1;
    bp[(n * 2 + 1) * B + tid] = s2;

    // fused deterministic reduction: release = fence + count; last RED arrivals reduce.
    __threadfence();
    __syncthreads();
    __shared__ int s_old;
    if (tid == 0) s_old = atomicAdd(&cnt_red[t], 1);
    __syncthreads();
    int old = s_old;
    if (old >= N_F - RED) {
        if (tid == 0) {
            while (__hip_atomic_load(cnt_red + t, __ATOMIC_RELAXED, __HIP_MEMORY_SCOPE_AGENT) < N_F)
                __builtin_amdgcn_s_sleep(32);
        }
        __syncthreads();
        __threadfence();   // acquire: make all blocks' bp visible
        int slice = old - (N_F - RED);
        float a1 = 0.f, a2 = 0.f;
        for (int i = slice; i < N_F; i += RED) {   // fixed order -> deterministic
            a1 += bp[(i * 2 + 0) * B + tid];
            a2 += bp[(i * 2 + 1) * B + tid];
        }
        p2[(slice * 2 + 0) * B + tid] = a1;
        p2[(slice * 2 + 1) * B + tid] = a2;
    }
}

__global__ __launch_bounds__(256) void f_upd(
    const unsigned short* __restrict__ hidbf, const float* __restrict__ p2,
    const float* __restrict__ gamma, const float* __restrict__ beta,
    const float* __restrict__ w2C, const int* __restrict__ jposC,
    const int* __restrict__ rsC,
    float* __restrict__ Sg, unsigned short* __restrict__ qbf, int t) {
    int n = blockIdx.x, tid = threadIdx.x;
    const float4* w24 = (const float4*)w2C;
    float S1 = 0.f, S2 = 0.f;
    #pragma unroll
    for (int k = 0; k < RED; ++k) {
        S1 += p2[(k * 2 + 0) * B + tid];
        S2 += p2[(k * 2 + 1) * B + tid];
    }
    float mu  = S1 * (1.0f / H);
    float var = S2 * (1.0f / H) - mu * mu;
    float rsq = rsqrtf(var + EPSF);
    float Sn[C];
    #pragma unroll
    for (int c = 0; c < C; ++c) {
        float v = bf2f(hidbf[(n * C + c) * B + tid]);
        v = (v - mu) * rsq * gamma[n * C + c] + beta[n * C + c];
        v = (v > 0.f) ? v : expm1f(v);
        Sn[c] = (t == 0) ? v : (Sg[(n * C + c) * B + tid] + v);
    }
    #pragma unroll
    for (int c = 0; c < C; ++c) Sg[(n * C + c) * B + tid] = Sn[c];
    if (t < LAYERS - 1) {
        int beg = rsC[n], end = rsC[n + 1];
        for (int p = beg; p < end; ++p) {
            int j = jposC[p];
            float4 u0 = w24[p * 2], u1 = w24[p * 2 + 1];
            float qv = u0.x * Sn[0] + u0.y * Sn[1] + u0.z * Sn[2] + u0.w * Sn[3]
                     + u1.x * Sn[4] + u1.y * Sn[5] + u1.z * Sn[6] + u1.w * Sn[7];
            qbf[j * B + tid] = f2bf(qv);
        }
    }
}

// ---------------- output ----------------

__global__ void f_zero_out(float* __restrict__ out) {
    int i = blockIdx.x * 256 + threadIdx.x;  // 750*256 float4 = 768000 floats
    ((float4*)out)[i] = make_float4(0.f, 0.f, 0.f, 0.f);
}

__global__ void f_out(const float* __restrict__ xT, const float* __restrict__ Sg,
                      const int* __restrict__ rsD, const int* __restrict__ eidD,
                      const int* __restrict__ srcv, const float* __restrict__ w2,
                      const float* __restrict__ b2, float* __restrict__ out) {
    int o = blockIdx.x, tid = threadIdx.x;
    const float4* w24 = (const float4*)w2;
    float acc = 0.f;
    int beg = rsD[o], end = rsD[o + 1];
    for (int k = beg; k < end; ++k) {
        int e = eidD[k];
        int s = srcv[e];
        float4 u0 = w24[e * 2], u1 = w24[e * 2 + 1];
        float dot = u0.x * Sg[(s * C + 0) * B + tid] + u0.y * Sg[(s * C + 1) * B + tid]
                  + u0.z * Sg[(s * C + 2) * B + tid] + u0.w * Sg[(s * C + 3) * B + tid]
                  + u1.x * Sg[(s * C + 4) * B + tid] + u1.y * Sg[(s * C + 5) * B + tid]
                  + u1.z * Sg[(s * C + 6) * B + tid] + u1.w * Sg[(s * C + 7) * B + tid];
        acc += xT[s * B + tid] + dot + (float)LAYERS * b2[e];
    }
    out[tid * N_ALL + (N_F + N_I + o)] = acc * (1.0f / LAYERS);
}

// ---------------- launch ----------------

static inline char* alignup(char* p) { return (char*)(((uintptr_t)p + 255) & ~(uintptr_t)255); }

extern "C" void kernel_launch(void* const* d_in, const int* in_sizes, int n_in,
                              void* d_out, int out_size, void* d_ws, size_t ws_size,
                              hipStream_t stream) {
    const float* x     = (const float*)d_in[0];
    const float* w1    = (const float*)d_in[1];
    const float* b1    = (const float*)d_in[2];
    const float* gamma = (const float*)d_in[3];
    const float* beta  = (const float*)d_in[4];
    const float* w2    = (const float*)d_in[5];
    const float* b2    = (const float*)d_in[6];
    const int*   ei    = (const int*)d_in[7];
    const int* srcv = ei;
    const int* dstv = ei + E_ALL;
    float* out = (float*)d_out;

    char* p = (char*)d_ws;
    unsigned short* qbf   = (unsigned short*)p; p += (size_t)E_FF * B * 2; p = alignup(p);
    unsigned short* hidbf = (unsigned short*)p; p += (size_t)H * B * 2;    p = alignup(p);
    float* Sg    = (float*)p; p += (size_t)H * B * 4;        p = alignup(p);
    float* baseG = (float*)p; p += (size_t)H * B * 4;        p = alignup(p);
    float* xT    = (float*)p; p += (size_t)N_ALL * B * 4;    p = alignup(p);
    float* bp    = (float*)p; p += (size_t)N_F * 2 * B * 4;  p = alignup(p);
    float* p2    = (float*)p; p += (size_t)RED * 2 * B * 4;  p = alignup(p);
    float* bbG   = (float*)p; p += (size_t)N_F * C * 4;      p = alignup(p);
    float* jw1   = (float*)p; p += (size_t)E_FF * C * 4;     p = alignup(p);
    float* w2C   = (float*)p; p += (size_t)E_FF * C * 4;     p = alignup(p);
    int* posB  = (int*)p; p += (size_t)E_FF * 4;  p = alignup(p);
    int* jposC = (int*)p; p += (size_t)E_FF * 4;  p = alignup(p);
    int* cnt_red = (int*)p; p += LAYERS * 4;      p = alignup(p);
    int* cntA = (int*)p; p += N_F * 4;        p = alignup(p);
    int* cntB = (int*)p; p += N_F * 4;        p = alignup(p);
    int* cntC = (int*)p; p += N_F * 4;        p = alignup(p);
    int* cntD = (int*)p; p += N_O * 4;        p = alignup(p);
    int* curA = (int*)p; p += N_F * 4;        p = alignup(p);
    int* curB = (int*)p; p += N_F * 4;        p = alignup(p);
    int* curC = (int*)p; p += N_F * 4;        p = alignup(p);
    int* curD = (int*)p; p += N_O * 4;        p = alignup(p);
    int* rsA  = (int*)p; p += (N_F + 1) * 4;  p = alignup(p);
    int* rsB2 = (int*)p; p += (N_F + 1) * 4;  p = alignup(p);
    int* rsC  = (int*)p; p += (N_F + 1) * 4;  p = alignup(p);
    int* rsD  = (int*)p; p += (N_O + 1) * 4;  p = alignup(p);
    int* eidA = (int*)p; p += (size_t)(E_FF + E_IF) * 4; p = alignup(p);
    int* eidC = (int*)p; p += (size_t)E_FF * 4; p = alignup(p);
    int* eidD = (int*)p; p += (size_t)E_FO * 4; p = alignup(p);

    hipLaunchKernelGGL(k_zero_cnt, dim3(1), dim3(1024), 0, stream, cntA, cntB, cntC, cntD, cnt_red);
    hipLaunchKernelGGL(k_count, dim3((E_ALL + 255) / 256), dim3(256), 0, stream,
                       srcv, dstv, cntA, cntB, cntC, cntD);
    hipLaunchKernelGGL(k_scan, dim3(4), dim3(1024), 0, stream,
                       cntA, cntB, cntC, cntD, rsA, rsB2, rsC, rsD, curA, curB, curC, curD);
    hipLaunchKernelGGL(k_fill, dim3((E_ALL + 255) / 256), dim3(256), 0, stream,
                       srcv, dstv, curA, curC, curD, eidA, eidC, eidD);
    hipLaunchKernelGGL(k_wsort, dim3(1125), dim3(256), 0, stream,
                       rsA, eidA, rsC, eidC, rsD, eidD);
    hipLaunchKernelGGL(k_posB, dim3((N_F + 255) / 256), dim3(256), 0, stream,
                       rsA, eidA, cntB, rsB2, w1, posB, jw1);
    hipLaunchKernelGGL(k_posC, dim3((E_FF + 255) / 256), dim3(256), 0, stream,
                       eidC, posB, w2, jposC, w2C);
    hipLaunchKernelGGL(k_xT, dim3((N_ALL + 31) / 32, B / 32), dim3(32, 32), 0, stream, x, xT);
    hipLaunchKernelGGL(k_base, dim3(N_F), dim3(256), 0, stream,
                       xT, w1, b1, b2, rsA, eidA, srcv, baseG, bbG);

    hipLaunchKernelGGL(f_zero_out, dim3(750), dim3(256), 0, stream, out);
    for (int t = 0; t < LAYERS; ++t) {
        hipLaunchKernelGGL(f_hidstat, dim3(N_F), dim3(256), 0, stream,
                           baseG, bbG, jw1, qbf, rsB2, hidbf, bp, p2, cnt_red, t);
        hipLaunchKernelGGL(f_upd, dim3(N_F), dim3(256), 0, stream,
                           hidbf, p2, gamma, beta, w2C, jposC, rsC, Sg, qbf, t);
    }
    hipLaunchKernelGGL(f_out, dim3(N_O), dim3(256), 0, stream,
                       xT, Sg, rsD, eidD, srcv, w2, b2, out);
}

// Round 11
// 776.992 us; speedup vs baseline: 3.5236x; 3.5236x over previous
//
#include <hip/hip_runtime.h>
#include <cmath>
#include <cstdint>

#define N_F    2000
#define N_I    500
#define N_O    500
#define N_ALL  3000
#define C      8
#define H      16000
#define B      256
#define E_FF   40000
#define E_IF   5000
#define E_FO   2000
#define E_ALL  47000
#define LAYERS 10
#define EPSF   1e-5f
#define RED    32     // f_red blocks / p2 slices

// ---- bf16 helpers (RNE) ----
static __device__ __forceinline__ unsigned short f2bf(float f) {
    unsigned int u = __float_as_uint(f);
    unsigned int r = (u + 0x7FFFu + ((u >> 16) & 1u)) >> 16;
    return (unsigned short)r;
}
static __device__ __forceinline__ float bf2f(unsigned short h) {
    return __uint_as_float(((unsigned int)h) << 16);
}

// ---------------- CSR build (deterministic after k_wsort) ----------------

__global__ void k_zero_cnt(int* cntA, int* cntB, int* cntC, int* cntD) {
    int tid = threadIdx.x;
    for (int i = tid; i < N_F; i += 1024) { cntA[i] = 0; cntB[i] = 0; cntC[i] = 0; }
    for (int i = tid; i < N_O; i += 1024) cntD[i] = 0;
}

__global__ void k_count(const int* __restrict__ src, const int* __restrict__ dst,
                        int* cntA, int* cntB, int* cntC, int* cntD) {
    int e = blockIdx.x * 256 + threadIdx.x;
    if (e >= E_ALL) return;
    int s = src[e], d = dst[e];
    if (e < E_FF)             { atomicAdd(&cntA[d], 1); atomicAdd(&cntB[d], 1); atomicAdd(&cntC[s], 1); }
    else if (e < E_FF + E_IF) { atomicAdd(&cntA[d], 1); }
    else                      { atomicAdd(&cntD[d - (N_F + N_I)], 1); }
}

// 4 single-block scans: A(dst,FF+IF), B(dst,FF only), C(src,FF), D(dst,FO)
__global__ void k_scan(const int* cntA, const int* cntB, const int* cntC, const int* cntD,
                       int* rsA, int* rsB2, int* rsC, int* rsD,
                       int* curA, int* curB, int* curC, int* curD) {
    const int* cnt; int* rs; int* cur; int len;
    if      (blockIdx.x == 0) { cnt = cntA; rs = rsA;  cur = curA; len = N_F; }
    else if (blockIdx.x == 1) { cnt = cntB; rs = rsB2; cur = curB; len = N_F; }
    else if (blockIdx.x == 2) { cnt = cntC; rs = rsC;  cur = curC; len = N_F; }
    else                      { cnt = cntD; rs = rsD;  cur = curD; len = N_O; }
    __shared__ int buf[1024];
    __shared__ int carry;
    int tid = threadIdx.x;
    if (tid == 0) carry = 0;
    __syncthreads();
    for (int base0 = 0; base0 < len; base0 += 1024) {
        int i = base0 + tid;
        int v = (i < len) ? cnt[i] : 0;
        buf[tid] = v;
        __syncthreads();
        for (int off = 1; off < 1024; off <<= 1) {
            int t = (tid >= off) ? buf[tid - off] : 0;
            __syncthreads();
            buf[tid] += t;
            __syncthreads();
        }
        int excl = carry + buf[tid] - v;
        if (i < len) { rs[i] = excl; cur[i] = excl; }
        int tot = buf[1023];
        __syncthreads();
        if (tid == 0) carry += tot;
        __syncthreads();
    }
    if (tid == 0) rs[len] = carry;
}

__global__ void k_fill(const int* __restrict__ src, const int* __restrict__ dst,
                       int* curA, int* curC, int* curD,
                       int* eidA, int* eidC, int* eidD) {
    int e = blockIdx.x * 256 + threadIdx.x;
    if (e >= E_ALL) return;
    int s = src[e], d = dst[e];
    if (e < E_FF) {
        int a = atomicAdd(&curA[d], 1); eidA[a] = e;
        int p = atomicAdd(&curC[s], 1); eidC[p] = e;
    } else if (e < E_FF + E_IF) {
        int a = atomicAdd(&curA[d], 1); eidA[a] = e;
    } else {
        int k = atomicAdd(&curD[d - (N_F + N_I)], 1); eidD[k] = e;
    }
}

// canonicalize: wave rank-sort each list ascending by edge id. A(2000), C(2000), D(500).
__global__ void k_wsort(const int* __restrict__ rsA, int* eidA,
                        const int* __restrict__ rsC, int* eidC,
                        const int* __restrict__ rsD, int* eidD) {
    int w = blockIdx.x * 4 + (threadIdx.x >> 6);
    int lane = threadIdx.x & 63;
    const int* rs; int* eid; int n;
    if      (w < 2000) { rs = rsA; eid = eidA; n = w; }
    else if (w < 4000) { rs = rsC; eid = eidC; n = w - 2000; }
    else if (w < 4500) { rs = rsD; eid = eidD; n = w - 4000; }
    else return;
    int beg = rs[n], end = rs[n + 1], len = end - beg;
    if (len <= 1) return;
    if (len <= 64) {
        int v = (lane < len) ? eid[beg + lane] : 0x7fffffff;
        int rank = 0;
        for (int j = 0; j < 64; ++j) {
            int o = __shfl(v, j, 64);
            rank += (o < v) ? 1 : 0;
        }
        if (lane < len) eid[beg + rank] = v;
    } else if (lane == 0) {
        for (int i = beg + 1; i < end; ++i) {
            int key = eid[i];
            int j = i - 1;
            while (j >= beg && eid[j] > key) { eid[j + 1] = eid[j]; --j; }
            eid[j + 1] = key;
        }
    }
}

// posB[e] = dst-CSR position j for FF edge e; jw1[j] = w1[e]  (FF edges are the
// first cntB[n] entries of node n's sorted A-list, since FF ids < IF ids)
__global__ void k_posB(const int* __restrict__ rsA, const int* __restrict__ eidA,
                       const int* __restrict__ cntB, const int* __restrict__ rsB2,
                       const float* __restrict__ w1, int* posB, float* jw1) {
    int n = blockIdx.x * 256 + threadIdx.x;
    if (n >= N_F) return;
    int a0 = rsA[n], j0 = rsB2[n], m = cntB[n];
    for (int k = 0; k < m; ++k) {
        int e = eidA[a0 + k];
        int j = j0 + k;
        posB[e] = j;
        #pragma unroll
        for (int c = 0; c < C; ++c) jw1[j * C + c] = w1[e * C + c];
    }
}

// jposC[p] = posB[eidC[p]]; w2C[p] = w2[eidC[p]]
__global__ void k_posC(const int* __restrict__ eidC, const int* __restrict__ posB,
                       const float* __restrict__ w2, int* jposC, float* w2C) {
    int p = blockIdx.x * 256 + threadIdx.x;
    if (p >= E_FF) return;
    int e = eidC[p];
    jposC[p] = posB[e];
    #pragma unroll
    for (int c = 0; c < C; ++c) w2C[p * C + c] = w2[e * C + c];
}

// ---------------- init ----------------

// x (B, N_ALL) -> xT (N_ALL, B)
__global__ void k_xT(const float* __restrict__ x, float* __restrict__ xT) {
    __shared__ float t[32][33];
    int tx = threadIdx.x, ty = threadIdx.y;
    int n = blockIdx.x * 32 + tx, b = blockIdx.y * 32 + ty;
    if (n < N_ALL) t[ty][tx] = x[b * N_ALL + n];
    __syncthreads();
    int n2 = blockIdx.x * 32 + ty, b2 = blockIdx.y * 32 + tx;
    if (n2 < N_ALL) xT[n2 * B + b2] = t[tx][ty];
}

// base[n][c][b] = sum_{FF+IF e->n} w1[e][c]*x[src_e][b] + b1[n*C+c]; bb[n][c] = sum w1[e][c]*b2[e]
__global__ void k_base(const float* __restrict__ xT, const float* __restrict__ w1,
                       const float* __restrict__ b1, const float* __restrict__ b2,
                       const int* __restrict__ rsA, const int* __restrict__ eidA,
                       const int* __restrict__ srcv,
                       float* __restrict__ baseG, float* __restrict__ bbG) {
    int n = blockIdx.x, tid = threadIdx.x;
    int beg = rsA[n], end = rsA[n + 1];
    float acc[C] = {0.f,0.f,0.f,0.f,0.f,0.f,0.f,0.f};
    float bba[C] = {0.f,0.f,0.f,0.f,0.f,0.f,0.f,0.f};
    const float4* w14 = (const float4*)w1;
    for (int a = beg; a < end; ++a) {
        int e = eidA[a];
        float xv = xT[srcv[e] * B + tid];
        float bv = b2[e];
        float4 u0 = w14[e * 2], u1 = w14[e * 2 + 1];
        acc[0] += u0.x * xv; acc[1] += u0.y * xv; acc[2] += u0.z * xv; acc[3] += u0.w * xv;
        acc[4] += u1.x * xv; acc[5] += u1.y * xv; acc[6] += u1.z * xv; acc[7] += u1.w * xv;
        bba[0] += u0.x * bv; bba[1] += u0.y * bv; bba[2] += u0.z * bv; bba[3] += u0.w * bv;
        bba[4] += u1.x * bv; bba[5] += u1.y * bv; bba[6] += u1.z * bv; bba[7] += u1.w * bv;
    }
    #pragma unroll
    for (int c = 0; c < C; ++c) baseG[(n * C + c) * B + tid] = acc[c] + b1[n * C + c];
    if (tid == 0) {
        #pragma unroll
        for (int c = 0; c < C; ++c) bbG[n * C + c] = bba[c];
    }
}

// ---------------- per-layer pipeline (3 kernels/layer, NO device-scope sync) ----------------
// Round-8/10 lesson: per-block __threadfence + atomic spin serializes at the
// non-coherent per-XCD L2 boundary (245us, VALUBusy 1%). Kernel boundaries are
// the cheap global sync (~4us). q stored in dst-CSR order j: f_hidstat reads a
// CONTIGUOUS range [rsB2[n], rsB2[n+1]); f_upd scatters to qbf[jposC[p]].

__global__ __launch_bounds__(256) void f_hidstat(
    const float* __restrict__ baseG, const float* __restrict__ bbG,
    const float* __restrict__ jw1, const unsigned short* __restrict__ qbf,
    const int* __restrict__ rsB2,
    unsigned short* __restrict__ hidbf, float* __restrict__ bp, int t) {
    int n = blockIdx.x, tid = threadIdx.x;
    const float4* jw14 = (const float4*)jw1;
    float tf = (float)t;
    float hid[C];
    #pragma unroll
    for (int c = 0; c < C; ++c) hid[c] = baseG[(n * C + c) * B + tid] + tf * bbG[n * C + c];
    if (t > 0) {
        int beg = rsB2[n], end = rsB2[n + 1];
        for (int j = beg; j < end; ++j) {
            float qv = bf2f(qbf[j * B + tid]);
            float4 u0 = jw14[j * 2], u1 = jw14[j * 2 + 1];
            hid[0] += u0.x * qv; hid[1] += u0.y * qv; hid[2] += u0.z * qv; hid[3] += u0.w * qv;
            hid[4] += u1.x * qv; hid[5] += u1.y * qv; hid[6] += u1.z * qv; hid[7] += u1.w * qv;
        }
    }
    float s1 = 0.f, s2 = 0.f;
    #pragma unroll
    for (int c = 0; c < C; ++c) {
        hidbf[(n * C + c) * B + tid] = f2bf(hid[c]);
        s1 += hid[c]; s2 += hid[c] * hid[c];
    }
    bp[(n * 2 + 0) * B + tid] = s1;
    bp[(n * 2 + 1) * B + tid] = s2;
}

// 32 blocks: slice k reduces nodes {k, k+32, ...} (fixed order -> deterministic)
__global__ __launch_bounds__(256) void f_red(const float* __restrict__ bp, float* __restrict__ p2) {
    int blk = blockIdx.x, tid = threadIdx.x;
    float a1 = 0.f, a2 = 0.f;
    for (int i = blk; i < N_F; i += RED) {
        a1 += bp[(i * 2 + 0) * B + tid];
        a2 += bp[(i * 2 + 1) * B + tid];
    }
    p2[(blk * 2 + 0) * B + tid] = a1;
    p2[(blk * 2 + 1) * B + tid] = a2;
}

__global__ __launch_bounds__(256) void f_upd(
    const unsigned short* __restrict__ hidbf, const float* __restrict__ p2,
    const float* __restrict__ gamma, const float* __restrict__ beta,
    const float* __restrict__ w2C, const int* __restrict__ jposC,
    const int* __restrict__ rsC,
    float* __restrict__ Sg, unsigned short* __restrict__ qbf, int t) {
    int n = blockIdx.x, tid = threadIdx.x;
    const float4* w24 = (const float4*)w2C;
    float S1 = 0.f, S2 = 0.f;
    #pragma unroll
    for (int k = 0; k < RED; ++k) {
        S1 += p2[(k * 2 + 0) * B + tid];
        S2 += p2[(k * 2 + 1) * B + tid];
    }
    float mu  = S1 * (1.0f / H);
    float var = S2 * (1.0f / H) - mu * mu;
    float rsq = rsqrtf(var + EPSF);
    float Sn[C];
    #pragma unroll
    for (int c = 0; c < C; ++c) {
        float v = bf2f(hidbf[(n * C + c) * B + tid]);
        v = (v - mu) * rsq * gamma[n * C + c] + beta[n * C + c];
        v = (v > 0.f) ? v : expm1f(v);
        Sn[c] = (t == 0) ? v : (Sg[(n * C + c) * B + tid] + v);
    }
    #pragma unroll
    for (int c = 0; c < C; ++c) Sg[(n * C + c) * B + tid] = Sn[c];
    if (t < LAYERS - 1) {
        int beg = rsC[n], end = rsC[n + 1];
        for (int p = beg; p < end; ++p) {
            int j = jposC[p];
            float4 u0 = w24[p * 2], u1 = w24[p * 2 + 1];
            float qv = u0.x * Sn[0] + u0.y * Sn[1] + u0.z * Sn[2] + u0.w * Sn[3]
                     + u1.x * Sn[4] + u1.y * Sn[5] + u1.z * Sn[6] + u1.w * Sn[7];
            qbf[j * B + tid] = f2bf(qv);
        }
    }
}

// ---------------- output ----------------

__global__ void f_zero_out(float* __restrict__ out) {
    int i = blockIdx.x * 256 + threadIdx.x;  // 750*256 float4 = 768000 floats
    ((float4*)out)[i] = make_float4(0.f, 0.f, 0.f, 0.f);
}

__global__ void f_out(const float* __restrict__ xT, const float* __restrict__ Sg,
                      const int* __restrict__ rsD, const int* __restrict__ eidD,
                      const int* __restrict__ srcv, const float* __restrict__ w2,
                      const float* __restrict__ b2, float* __restrict__ out) {
    int o = blockIdx.x, tid = threadIdx.x;
    const float4* w24 = (const float4*)w2;
    float acc = 0.f;
    int beg = rsD[o], end = rsD[o + 1];
    for (int k = beg; k < end; ++k) {
        int e = eidD[k];
        int s = srcv[e];
        float4 u0 = w24[e * 2], u1 = w24[e * 2 + 1];
        float dot = u0.x * Sg[(s * C + 0) * B + tid] + u0.y * Sg[(s * C + 1) * B + tid]
                  + u0.z * Sg[(s * C + 2) * B + tid] + u0.w * Sg[(s * C + 3) * B + tid]
                  + u1.x * Sg[(s * C + 4) * B + tid] + u1.y * Sg[(s * C + 5) * B + tid]
                  + u1.z * Sg[(s * C + 6) * B + tid] + u1.w * Sg[(s * C + 7) * B + tid];
        acc += xT[s * B + tid] + dot + (float)LAYERS * b2[e];
    }
    out[tid * N_ALL + (N_F + N_I + o)] = acc * (1.0f / LAYERS);
}

// ---------------- launch ----------------

static inline char* alignup(char* p) { return (char*)(((uintptr_t)p + 255) & ~(uintptr_t)255); }

extern "C" void kernel_launch(void* const* d_in, const int* in_sizes, int n_in,
                              void* d_out, int out_size, void* d_ws, size_t ws_size,
                              hipStream_t stream) {
    const float* x     = (const float*)d_in[0];
    const float* w1    = (const float*)d_in[1];
    const float* b1    = (const float*)d_in[2];
    const float* gamma = (const float*)d_in[3];
    const float* beta  = (const float*)d_in[4];
    const float* w2    = (const float*)d_in[5];
    const float* b2    = (const float*)d_in[6];
    const int*   ei    = (const int*)d_in[7];
    const int* srcv = ei;
    const int* dstv = ei + E_ALL;
    float* out = (float*)d_out;

    char* p = (char*)d_ws;
    unsigned short* qbf   = (unsigned short*)p; p += (size_t)E_FF * B * 2; p = alignup(p);
    unsigned short* hidbf = (unsigned short*)p; p += (size_t)H * B * 2;    p = alignup(p);
    float* Sg    = (float*)p; p += (size_t)H * B * 4;        p = alignup(p);
    float* baseG = (float*)p; p += (size_t)H * B * 4;        p = alignup(p);
    float* xT    = (float*)p; p += (size_t)N_ALL * B * 4;    p = alignup(p);
    float* bp    = (float*)p; p += (size_t)N_F * 2 * B * 4;  p = alignup(p);
    float* p2    = (float*)p; p += (size_t)RED * 2 * B * 4;  p = alignup(p);
    float* bbG   = (float*)p; p += (size_t)N_F * C * 4;      p = alignup(p);
    float* jw1   = (float*)p; p += (size_t)E_FF * C * 4;     p = alignup(p);
    float* w2C   = (float*)p; p += (size_t)E_FF * C * 4;     p = alignup(p);
    int* posB  = (int*)p; p += (size_t)E_FF * 4;  p = alignup(p);
    int* jposC = (int*)p; p += (size_t)E_FF * 4;  p = alignup(p);
    int* cntA = (int*)p; p += N_F * 4;        p = alignup(p);
    int* cntB = (int*)p; p += N_F * 4;        p = alignup(p);
    int* cntC = (int*)p; p += N_F * 4;        p = alignup(p);
    int* cntD = (int*)p; p += N_O * 4;        p = alignup(p);
    int* curA = (int*)p; p += N_F * 4;        p = alignup(p);
    int* curB = (int*)p; p += N_F * 4;        p = alignup(p);
    int* curC = (int*)p; p += N_F * 4;        p = alignup(p);
    int* curD = (int*)p; p += N_O * 4;        p = alignup(p);
    int* rsA  = (int*)p; p += (N_F + 1) * 4;  p = alignup(p);
    int* rsB2 = (int*)p; p += (N_F + 1) * 4;  p = alignup(p);
    int* rsC  = (int*)p; p += (N_F + 1) * 4;  p = alignup(p);
    int* rsD  = (int*)p; p += (N_O + 1) * 4;  p = alignup(p);
    int* eidA = (int*)p; p += (size_t)(E_FF + E_IF) * 4; p = alignup(p);
    int* eidC = (int*)p; p += (size_t)E_FF * 4; p = alignup(p);
    int* eidD = (int*)p; p += (size_t)E_FO * 4; p = alignup(p);

    hipLaunchKernelGGL(k_zero_cnt, dim3(1), dim3(1024), 0, stream, cntA, cntB, cntC, cntD);
    hipLaunchKernelGGL(k_count, dim3((E_ALL + 255) / 256), dim3(256), 0, stream,
                       srcv, dstv, cntA, cntB, cntC, cntD);
    hipLaunchKernelGGL(k_scan, dim3(4), dim3(1024), 0, stream,
                       cntA, cntB, cntC, cntD, rsA, rsB2, rsC, rsD, curA, curB, curC, curD);
    hipLaunchKernelGGL(k_fill, dim3((E_ALL + 255) / 256), dim3(256), 0, stream,
                       srcv, dstv, curA, curC, curD, eidA, eidC, eidD);
    hipLaunchKernelGGL(k_wsort, dim3(1125), dim3(256), 0, stream,
                       rsA, eidA, rsC, eidC, rsD, eidD);
    hipLaunchKernelGGL(k_posB, dim3((N_F + 255) / 256), dim3(256), 0, stream,
                       rsA, eidA, cntB, rsB2, w1, posB, jw1);
    hipLaunchKernelGGL(k_posC, dim3((E_FF + 255) / 256), dim3(256), 0, stream,
                       eidC, posB, w2, jposC, w2C);
    hipLaunchKernelGGL(k_xT, dim3((N_ALL + 31) / 32, B / 32), dim3(32, 32), 0, stream, x, xT);
    hipLaunchKernelGGL(k_base, dim3(N_F), dim3(256), 0, stream,
                       xT, w1, b1, b2, rsA, eidA, srcv, baseG, bbG);

    hipLaunchKernelGGL(f_zero_out, dim3(750), dim3(256), 0, stream, out);
    for (int t = 0; t < LAYERS; ++t) {
        hipLaunchKernelGGL(f_hidstat, dim3(N_F), dim3(256), 0, stream,
                           baseG, bbG, jw1, qbf, rsB2, hidbf, bp, t);
        hipLaunchKernelGGL(f_red, dim3(RED), dim3(256), 0, stream, bp, p2);
        hipLaunchKernelGGL(f_upd, dim3(N_F), dim3(256), 0, stream,
                           hidbf, p2, gamma, beta, w2C, jposC, rsC, Sg, qbf, t);
    }
    hipLaunchKernelGGL(f_out, dim3(N_O), dim3(256), 0, stream,
                       xT, Sg, rsD, eidD, srcv, w2, b2, out);
}

// Round 12
// 717.089 us; speedup vs baseline: 3.8180x; 1.0835x over previous
//
#include <hip/hip_runtime.h>
#include <cmath>
#include <cstdint>

#define N_F    2000
#define N_I    500
#define N_O    500
#define N_ALL  3000
#define C      8
#define H      16000
#define B      256
#define E_FF   40000
#define E_IF   5000
#define E_FO   2000
#define E_ALL  47000
#define LAYERS 10
#define EPSF   1e-5f
#define RED    32     // f_red blocks / p2 slices

// ---- bf16 helpers (RNE) ----
static __device__ __forceinline__ unsigned short f2bf(float f) {
    unsigned int u = __float_as_uint(f);
    unsigned int r = (u + 0x7FFFu + ((u >> 16) & 1u)) >> 16;
    return (unsigned short)r;
}
static __device__ __forceinline__ float bf2f(unsigned short h) {
    return __uint_as_float(((unsigned int)h) << 16);
}

// ---------------- CSR build (deterministic after k_wsort) ----------------

__global__ void k_zero_cnt(int* cntA, int* cntB, int* cntC, int* cntD) {
    int tid = threadIdx.x;
    for (int i = tid; i < N_F; i += 1024) { cntA[i] = 0; cntB[i] = 0; cntC[i] = 0; }
    for (int i = tid; i < N_O; i += 1024) cntD[i] = 0;
}

__global__ void k_count(const int* __restrict__ src, const int* __restrict__ dst,
                        int* cntA, int* cntB, int* cntC, int* cntD) {
    int e = blockIdx.x * 256 + threadIdx.x;
    if (e >= E_ALL) return;
    int s = src[e], d = dst[e];
    if (e < E_FF)             { atomicAdd(&cntA[d], 1); atomicAdd(&cntB[d], 1); atomicAdd(&cntC[s], 1); }
    else if (e < E_FF + E_IF) { atomicAdd(&cntA[d], 1); }
    else                      { atomicAdd(&cntD[d - (N_F + N_I)], 1); }
}

// 4 single-block scans: A(dst,FF+IF), B(dst,FF only), C(src,FF), D(dst,FO)
__global__ void k_scan(const int* cntA, const int* cntB, const int* cntC, const int* cntD,
                       int* rsA, int* rsB2, int* rsC, int* rsD,
                       int* curA, int* curB, int* curC, int* curD) {
    const int* cnt; int* rs; int* cur; int len;
    if      (blockIdx.x == 0) { cnt = cntA; rs = rsA;  cur = curA; len = N_F; }
    else if (blockIdx.x == 1) { cnt = cntB; rs = rsB2; cur = curB; len = N_F; }
    else if (blockIdx.x == 2) { cnt = cntC; rs = rsC;  cur = curC; len = N_F; }
    else                      { cnt = cntD; rs = rsD;  cur = curD; len = N_O; }
    __shared__ int buf[1024];
    __shared__ int carry;
    int tid = threadIdx.x;
    if (tid == 0) carry = 0;
    __syncthreads();
    for (int base0 = 0; base0 < len; base0 += 1024) {
        int i = base0 + tid;
        int v = (i < len) ? cnt[i] : 0;
        buf[tid] = v;
        __syncthreads();
        for (int off = 1; off < 1024; off <<= 1) {
            int t = (tid >= off) ? buf[tid - off] : 0;
            __syncthreads();
            buf[tid] += t;
            __syncthreads();
        }
        int excl = carry + buf[tid] - v;
        if (i < len) { rs[i] = excl; cur[i] = excl; }
        int tot = buf[1023];
        __syncthreads();
        if (tid == 0) carry += tot;
        __syncthreads();
    }
    if (tid == 0) rs[len] = carry;
}

__global__ void k_fill(const int* __restrict__ src, const int* __restrict__ dst,
                       int* curA, int* curC, int* curD,
                       int* eidA, int* eidC, int* eidD) {
    int e = blockIdx.x * 256 + threadIdx.x;
    if (e >= E_ALL) return;
    int s = src[e], d = dst[e];
    if (e < E_FF) {
        int a = atomicAdd(&curA[d], 1); eidA[a] = e;
        int p = atomicAdd(&curC[s], 1); eidC[p] = e;
    } else if (e < E_FF + E_IF) {
        int a = atomicAdd(&curA[d], 1); eidA[a] = e;
    } else {
        int k = atomicAdd(&curD[d - (N_F + N_I)], 1); eidD[k] = e;
    }
}

// canonicalize: wave rank-sort each list ascending by edge id. A(2000), C(2000), D(500).
__global__ void k_wsort(const int* __restrict__ rsA, int* eidA,
                        const int* __restrict__ rsC, int* eidC,
                        const int* __restrict__ rsD, int* eidD) {
    int w = blockIdx.x * 4 + (threadIdx.x >> 6);
    int lane = threadIdx.x & 63;
    const int* rs; int* eid; int n;
    if      (w < 2000) { rs = rsA; eid = eidA; n = w; }
    else if (w < 4000) { rs = rsC; eid = eidC; n = w - 2000; }
    else if (w < 4500) { rs = rsD; eid = eidD; n = w - 4000; }
    else return;
    int beg = rs[n], end = rs[n + 1], len = end - beg;
    if (len <= 1) return;
    if (len <= 64) {
        int v = (lane < len) ? eid[beg + lane] : 0x7fffffff;
        int rank = 0;
        for (int j = 0; j < 64; ++j) {
            int o = __shfl(v, j, 64);
            rank += (o < v) ? 1 : 0;
        }
        if (lane < len) eid[beg + rank] = v;
    } else if (lane == 0) {
        for (int i = beg + 1; i < end; ++i) {
            int key = eid[i];
            int j = i - 1;
            while (j >= beg && eid[j] > key) { eid[j + 1] = eid[j]; --j; }
            eid[j + 1] = key;
        }
    }
}

// posB[e] = dst-CSR position j for FF edge e; jw1[j] = w1[e].
// One 64-lane wave per node (round-11 lesson: serial thread-per-node = 50us @0.3% occ).
// FF edges are the first cntB[n] entries of node n's sorted A-list (FF ids < IF ids).
__global__ void k_posB(const int* __restrict__ rsA, const int* __restrict__ eidA,
                       const int* __restrict__ cntB, const int* __restrict__ rsB2,
                       const float* __restrict__ w1, int* posB, float* jw1) {
    int w = blockIdx.x * 4 + (threadIdx.x >> 6);
    int lane = threadIdx.x & 63;
    if (w >= N_F) return;
    int a0 = rsA[w], j0 = rsB2[w], m = cntB[w];
    const float4* w14 = (const float4*)w1;
    float4* jw14 = (float4*)jw1;
    for (int k = lane; k < m; k += 64) {
        int e = eidA[a0 + k];
        int j = j0 + k;
        posB[e] = j;
        jw14[j * 2]     = w14[e * 2];
        jw14[j * 2 + 1] = w14[e * 2 + 1];
    }
}

// jposC[p] = posB[eidC[p]]; w2C[p] = w2[eidC[p]]
__global__ void k_posC(const int* __restrict__ eidC, const int* __restrict__ posB,
                       const float* __restrict__ w2, int* jposC, float* w2C) {
    int p = blockIdx.x * 256 + threadIdx.x;
    if (p >= E_FF) return;
    int e = eidC[p];
    jposC[p] = posB[e];
    float4 u0 = ((const float4*)w2)[e * 2], u1 = ((const float4*)w2)[e * 2 + 1];
    ((float4*)w2C)[p * 2]     = u0;
    ((float4*)w2C)[p * 2 + 1] = u1;
}

// ---------------- init ----------------

// x (B, N_ALL) -> xT (N_ALL, B)
__global__ void k_xT(const float* __restrict__ x, float* __restrict__ xT) {
    __shared__ float t[32][33];
    int tx = threadIdx.x, ty = threadIdx.y;
    int n = blockIdx.x * 32 + tx, b = blockIdx.y * 32 + ty;
    if (n < N_ALL) t[ty][tx] = x[b * N_ALL + n];
    __syncthreads();
    int n2 = blockIdx.x * 32 + ty, b2 = blockIdx.y * 32 + tx;
    if (n2 < N_ALL) xT[n2 * B + b2] = t[tx][ty];
}

// base (bf16) and bb (f32)
__global__ void k_base(const float* __restrict__ xT, const float* __restrict__ w1,
                       const float* __restrict__ b1, const float* __restrict__ b2,
                       const int* __restrict__ rsA, const int* __restrict__ eidA,
                       const int* __restrict__ srcv,
                       unsigned short* __restrict__ baseG, float* __restrict__ bbG) {
    int n = blockIdx.x, tid = threadIdx.x;
    int beg = rsA[n], end = rsA[n + 1];
    float acc[C] = {0.f,0.f,0.f,0.f,0.f,0.f,0.f,0.f};
    float bba[C] = {0.f,0.f,0.f,0.f,0.f,0.f,0.f,0.f};
    const float4* w14 = (const float4*)w1;
    for (int a = beg; a < end; ++a) {
        int e = eidA[a];
        float xv = xT[srcv[e] * B + tid];
        float bv = b2[e];
        float4 u0 = w14[e * 2], u1 = w14[e * 2 + 1];
        acc[0] += u0.x * xv; acc[1] += u0.y * xv; acc[2] += u0.z * xv; acc[3] += u0.w * xv;
        acc[4] += u1.x * xv; acc[5] += u1.y * xv; acc[6] += u1.z * xv; acc[7] += u1.w * xv;
        bba[0] += u0.x * bv; bba[1] += u0.y * bv; bba[2] += u0.z * bv; bba[3] += u0.w * bv;
        bba[4] += u1.x * bv; bba[5] += u1.y * bv; bba[6] += u1.z * bv; bba[7] += u1.w * bv;
    }
    #pragma unroll
    for (int c = 0; c < C; ++c) baseG[(n * C + c) * B + tid] = f2bf(acc[c] + b1[n * C + c]);
    if (tid == 0) {
        #pragma unroll
        for (int c = 0; c < C; ++c) bbG[n * C + c] = bba[c];
    }
}

// ---------------- per-layer pipeline (3 kernels/layer, NO device-scope sync) ----------------
// q in dst-CSR order: f_hidstat reads CONTIGUOUS [rsB2[n], rsB2[n+1]); f_upd scatters.
// bf16: qbf, hidbf, baseG, Sg. f32 accumulation everywhere.

__global__ __launch_bounds__(256) void f_hidstat(
    const unsigned short* __restrict__ baseG, const float* __restrict__ bbG,
    const float* __restrict__ jw1, const unsigned short* __restrict__ qbf,
    const int* __restrict__ rsB2,
    unsigned short* __restrict__ hidbf, float* __restrict__ bp, int t) {
    int n = blockIdx.x, tid = threadIdx.x;
    const float4* jw14 = (const float4*)jw1;
    float tf = (float)t;
    float hid[C];
    #pragma unroll
    for (int c = 0; c < C; ++c)
        hid[c] = bf2f(baseG[(n * C + c) * B + tid]) + tf * bbG[n * C + c];
    if (t > 0) {
        int beg = rsB2[n], end = rsB2[n + 1];
        for (int j = beg; j < end; ++j) {
            float qv = bf2f(qbf[j * B + tid]);
            float4 u0 = jw14[j * 2], u1 = jw14[j * 2 + 1];
            hid[0] += u0.x * qv; hid[1] += u0.y * qv; hid[2] += u0.z * qv; hid[3] += u0.w * qv;
            hid[4] += u1.x * qv; hid[5] += u1.y * qv; hid[6] += u1.z * qv; hid[7] += u1.w * qv;
        }
    }
    float s1 = 0.f, s2 = 0.f;
    #pragma unroll
    for (int c = 0; c < C; ++c) {
        hidbf[(n * C + c) * B + tid] = f2bf(hid[c]);
        s1 += hid[c]; s2 += hid[c] * hid[c];
    }
    bp[(n * 2 + 0) * B + tid] = s1;
    bp[(n * 2 + 1) * B + tid] = s2;
}

// 32 blocks: slice k reduces nodes {k, k+32, ...} (fixed order -> deterministic)
__global__ __launch_bounds__(256) void f_red(const float* __restrict__ bp, float* __restrict__ p2) {
    int blk = blockIdx.x, tid = threadIdx.x;
    float a1 = 0.f, a2 = 0.f;
    for (int i = blk; i < N_F; i += RED) {
        a1 += bp[(i * 2 + 0) * B + tid];
        a2 += bp[(i * 2 + 1) * B + tid];
    }
    p2[(blk * 2 + 0) * B + tid] = a1;
    p2[(blk * 2 + 1) * B + tid] = a2;
}

__global__ __launch_bounds__(256) void f_upd(
    const unsigned short* __restrict__ hidbf, const float* __restrict__ p2,
    const float* __restrict__ gamma, const float* __restrict__ beta,
    const float* __restrict__ w2C, const int* __restrict__ jposC,
    const int* __restrict__ rsC,
    unsigned short* __restrict__ Sg, unsigned short* __restrict__ qbf, int t) {
    int n = blockIdx.x, tid = threadIdx.x;
    const float4* w24 = (const float4*)w2C;
    float S1 = 0.f, S2 = 0.f;
    #pragma unroll
    for (int k = 0; k < RED; ++k) {
        S1 += p2[(k * 2 + 0) * B + tid];
        S2 += p2[(k * 2 + 1) * B + tid];
    }
    float mu  = S1 * (1.0f / H);
    float var = S2 * (1.0f / H) - mu * mu;
    float rsq = rsqrtf(var + EPSF);
    float Sn[C];
    #pragma unroll
    for (int c = 0; c < C; ++c) {
        float v = bf2f(hidbf[(n * C + c) * B + tid]);
        v = (v - mu) * rsq * gamma[n * C + c] + beta[n * C + c];
        v = (v > 0.f) ? v : expm1f(v);
        Sn[c] = (t == 0) ? v : (bf2f(Sg[(n * C + c) * B + tid]) + v);
    }
    #pragma unroll
    for (int c = 0; c < C; ++c) Sg[(n * C + c) * B + tid] = f2bf(Sn[c]);
    if (t < LAYERS - 1) {
        int beg = rsC[n], end = rsC[n + 1];
        for (int p = beg; p < end; ++p) {
            int j = jposC[p];
            float4 u0 = w24[p * 2], u1 = w24[p * 2 + 1];
            float qv = u0.x * Sn[0] + u0.y * Sn[1] + u0.z * Sn[2] + u0.w * Sn[3]
                     + u1.x * Sn[4] + u1.y * Sn[5] + u1.z * Sn[6] + u1.w * Sn[7];
            qbf[j * B + tid] = f2bf(qv);
        }
    }
}

// ---------------- output ----------------

__global__ void f_zero_out(float* __restrict__ out) {
    int i = blockIdx.x * 256 + threadIdx.x;  // 750*256 float4 = 768000 floats
    ((float4*)out)[i] = make_float4(0.f, 0.f, 0.f, 0.f);
}

__global__ void f_out(const float* __restrict__ xT, const unsigned short* __restrict__ Sg,
                      const int* __restrict__ rsD, const int* __restrict__ eidD,
                      const int* __restrict__ srcv, const float* __restrict__ w2,
                      const float* __restrict__ b2, float* __restrict__ out) {
    int o = blockIdx.x, tid = threadIdx.x;
    const float4* w24 = (const float4*)w2;
    float acc = 0.f;
    int beg = rsD[o], end = rsD[o + 1];
    for (int k = beg; k < end; ++k) {
        int e = eidD[k];
        int s = srcv[e];
        float4 u0 = w24[e * 2], u1 = w24[e * 2 + 1];
        float dot = u0.x * bf2f(Sg[(s * C + 0) * B + tid]) + u0.y * bf2f(Sg[(s * C + 1) * B + tid])
                  + u0.z * bf2f(Sg[(s * C + 2) * B + tid]) + u0.w * bf2f(Sg[(s * C + 3) * B + tid])
                  + u1.x * bf2f(Sg[(s * C + 4) * B + tid]) + u1.y * bf2f(Sg[(s * C + 5) * B + tid])
                  + u1.z * bf2f(Sg[(s * C + 6) * B + tid]) + u1.w * bf2f(Sg[(s * C + 7) * B + tid]);
        acc += xT[s * B + tid] + dot + (float)LAYERS * b2[e];
    }
    out[tid * N_ALL + (N_F + N_I + o)] = acc * (1.0f / LAYERS);
}

// ---------------- launch ----------------

static inline char* alignup(char* p) { return (char*)(((uintptr_t)p + 255) & ~(uintptr_t)255); }

extern "C" void kernel_launch(void* const* d_in, const int* in_sizes, int n_in,
                              void* d_out, int out_size, void* d_ws, size_t ws_size,
                              hipStream_t stream) {
    const float* x     = (const float*)d_in[0];
    const float* w1    = (const float*)d_in[1];
    const float* b1    = (const float*)d_in[2];
    const float* gamma = (const float*)d_in[3];
    const float* beta  = (const float*)d_in[4];
    const float* w2    = (const float*)d_in[5];
    const float* b2    = (const float*)d_in[6];
    const int*   ei    = (const int*)d_in[7];
    const int* srcv = ei;
    const int* dstv = ei + E_ALL;
    float* out = (float*)d_out;

    char* p = (char*)d_ws;
    unsigned short* qbf   = (unsigned short*)p; p += (size_t)E_FF * B * 2; p = alignup(p);
    unsigned short* hidbf = (unsigned short*)p; p += (size_t)H * B * 2;    p = alignup(p);
    unsigned short* Sg    = (unsigned short*)p; p += (size_t)H * B * 2;    p = alignup(p);
    unsigned short* baseG = (unsigned short*)p; p += (size_t)H * B * 2;    p = alignup(p);
    float* xT    = (float*)p; p += (size_t)N_ALL * B * 4;    p = alignup(p);
    float* bp    = (float*)p; p += (size_t)N_F * 2 * B * 4;  p = alignup(p);
    float* p2    = (float*)p; p += (size_t)RED * 2 * B * 4;  p = alignup(p);
    float* bbG   = (float*)p; p += (size_t)N_F * C * 4;      p = alignup(p);
    float* jw1   = (float*)p; p += (size_t)E_FF * C * 4;     p = alignup(p);
    float* w2C   = (float*)p; p += (size_t)E_FF * C * 4;     p = alignup(p);
    int* posB  = (int*)p; p += (size_t)E_FF * 4;  p = alignup(p);
    int* jposC = (int*)p; p += (size_t)E_FF * 4;  p = alignup(p);
    int* cntA = (int*)p; p += N_F * 4;        p = alignup(p);
    int* cntB = (int*)p; p += N_F * 4;        p = alignup(p);
    int* cntC = (int*)p; p += N_F * 4;        p = alignup(p);
    int* cntD = (int*)p; p += N_O * 4;        p = alignup(p);
    int* curA = (int*)p; p += N_F * 4;        p = alignup(p);
    int* curB = (int*)p; p += N_F * 4;        p = alignup(p);
    int* curC = (int*)p; p += N_F * 4;        p = alignup(p);
    int* curD = (int*)p; p += N_O * 4;        p = alignup(p);
    int* rsA  = (int*)p; p += (N_F + 1) * 4;  p = alignup(p);
    int* rsB2 = (int*)p; p += (N_F + 1) * 4;  p = alignup(p);
    int* rsC  = (int*)p; p += (N_F + 1) * 4;  p = alignup(p);
    int* rsD  = (int*)p; p += (N_O + 1) * 4;  p = alignup(p);
    int* eidA = (int*)p; p += (size_t)(E_FF + E_IF) * 4; p = alignup(p);
    int* eidC = (int*)p; p += (size_t)E_FF * 4; p = alignup(p);
    int* eidD = (int*)p; p += (size_t)E_FO * 4; p = alignup(p);

    hipLaunchKernelGGL(k_zero_cnt, dim3(1), dim3(1024), 0, stream, cntA, cntB, cntC, cntD);
    hipLaunchKernelGGL(k_count, dim3((E_ALL + 255) / 256), dim3(256), 0, stream,
                       srcv, dstv, cntA, cntB, cntC, cntD);
    hipLaunchKernelGGL(k_scan, dim3(4), dim3(1024), 0, stream,
                       cntA, cntB, cntC, cntD, rsA, rsB2, rsC, rsD, curA, curB, curC, curD);
    hipLaunchKernelGGL(k_fill, dim3((E_ALL + 255) / 256), dim3(256), 0, stream,
                       srcv, dstv, curA, curC, curD, eidA, eidC, eidD);
    hipLaunchKernelGGL(k_wsort, dim3(1125), dim3(256), 0, stream,
                       rsA, eidA, rsC, eidC, rsD, eidD);
    hipLaunchKernelGGL(k_posB, dim3((N_F + 3) / 4), dim3(256), 0, stream,
                       rsA, eidA, cntB, rsB2, w1, posB, jw1);
    hipLaunchKernelGGL(k_posC, dim3((E_FF + 255) / 256), dim3(256), 0, stream,
                       eidC, posB, w2, jposC, w2C);
    hipLaunchKernelGGL(k_xT, dim3((N_ALL + 31) / 32, B / 32), dim3(32, 32), 0, stream, x, xT);
    hipLaunchKernelGGL(k_base, dim3(N_F), dim3(256), 0, stream,
                       xT, w1, b1, b2, rsA, eidA, srcv, baseG, bbG);

    hipLaunchKernelGGL(f_zero_out, dim3(750), dim3(256), 0, stream, out);
    for (int t = 0; t < LAYERS; ++t) {
        hipLaunchKernelGGL(f_hidstat, dim3(N_F), dim3(256), 0, stream,
                           baseG, bbG, jw1, qbf, rsB2, hidbf, bp, t);
        hipLaunchKernelGGL(f_red, dim3(RED), dim3(256), 0, stream, bp, p2);
        hipLaunchKernelGGL(f_upd, dim3(N_F), dim3(256), 0, stream,
                           hidbf, p2, gamma, beta, w2C, jposC, rsC, Sg, qbf, t);
    }
    hipLaunchKernelGGL(f_out, dim3(N_O), dim3(256), 0, stream,
                       xT, Sg, rsD, eidD, srcv, w2, b2, out);
}